// Round 5
// baseline (225.951 us; speedup 1.0000x reference)
//
#include <hip/hip_runtime.h>

typedef __attribute__((ext_vector_type(8))) short bf16x8;
typedef __attribute__((ext_vector_type(4))) float f32x4;

__device__ __forceinline__ unsigned f2bf(float f) {
    union { float f; unsigned u; } v; v.f = f;
    return (v.u + 0x7FFFu + ((v.u >> 16) & 1u)) >> 16;
}

// prep: whT[n][k] = bf16(Wh[k][n]); block=k (coalesced read), thread=n
__global__ void prep_whT(const float* __restrict__ Wh, ushort* __restrict__ whT) {
    int k = blockIdx.x;
    int n = threadIdx.x;
    whT[n * 256 + k] = (ushort)f2bf(Wh[k * 256 + n]);
}

#define NTILE 2048
#define NBLK  683

// persistent: each block sweeps tiles {b, b+683, b+1366}, prefetching the next
// tile's x into registers while finishing the current one.
__global__ __launch_bounds__(256, 3) void ccsa_gemm(
    const float* __restrict__ x, const ushort* __restrict__ whT,
    const float* __restrict__ bh, const float* __restrict__ gamma,
    float* __restrict__ out)
{
    __shared__ char lds[32768];              // A tile 64x256 bf16, XOR-swizzled
    const int tid  = threadIdx.x;
    const int lane = tid & 63;
    const int wv   = tid >> 6;
    const int r15  = lane & 15;
    const int g    = lane >> 4;

    const float gm = gamma[0];

    // whT fragment pointers (tile-invariant): A-operand rows n = wv*64+ni*16+r15
    const ushort* bp[4];
#pragma unroll
    for (int ni = 0; ni < 4; ++ni)
        bp[ni] = whT + (wv * 64 + ni * 16 + r15) * 256 + g * 8;

    // bias: 4 consecutive output cols per lane (n = wv*64+ni*16+g*4+rr)
    float4 bias4[4];
#pragma unroll
    for (int ni = 0; ni < 4; ++ni)
        bias4[ni] = *(const float4*)(bh + wv * 64 + ni * 16 + g * 4);

    float4 ld[16];
    long t = blockIdx.x;

    // ---- prologue: stage tile t (only exposed-latency staging) ----
    {
        const float* src = x + t * 16384 + tid * 4;
#pragma unroll
        for (int i = 0; i < 16; ++i) ld[i] = *(const float4*)(src + i * 1024);
    }
#pragma unroll
    for (int i = 0; i < 16; ++i) {
        int row = i * 4 + wv;
        int addr = row * 512 + ((lane * 8) ^ ((row & 7) << 4));
        uint2 pk;
        pk.x = f2bf(ld[i].x) | (f2bf(ld[i].y) << 16);
        pk.y = f2bf(ld[i].z) | (f2bf(ld[i].w) << 16);
        *(uint2*)(lds + addr) = pk;
    }
    __syncthreads();

    while (true) {
        const long t2 = t + NBLK;
        const bool pf = (t2 < NTILE);

        f32x4 acc[4][4] = {};   // [mi][ni]; D rows = n (whT), D cols = m (x)

#pragma unroll
        for (int ksl = 0; ksl < 8; ++ksl) {
            bf16x8 bc[4], af[4];
#pragma unroll
            for (int ni = 0; ni < 4; ++ni)
                bc[ni] = *(const bf16x8*)(bp[ni] + ksl * 32);
            const int ko = (ksl * 64 + g * 16) ^ ((r15 & 7) << 4);
#pragma unroll
            for (int mi = 0; mi < 4; ++mi)
                af[mi] = *(const bf16x8*)(lds + (mi * 16 + r15) * 512 + ko);
#pragma unroll
            for (int mi = 0; mi < 4; ++mi)
#pragma unroll
                for (int ni = 0; ni < 4; ++ni)
                    acc[mi][ni] = __builtin_amdgcn_mfma_f32_16x16x32_bf16(
                        bc[ni], af[mi], acc[mi][ni], 0, 0, 0);
        }

        // prefetch next tile into registers; consumed after epilogue + barrier
        if (pf) {
            const float* src = x + t2 * 16384 + tid * 4;
#pragma unroll
            for (int i = 0; i < 16; ++i) ld[i] = *(const float4*)(src + i * 1024);
        }

        // ---- epilogue: out = gm*(acc + bias) + x, float4 stores ----
        const long row0 = t * 64;
#pragma unroll
        for (int mi = 0; mi < 4; ++mi) {
            const int row = mi * 16 + r15;
            const int rb  = row * 512;
            const int sw  = (row & 7) << 4;
#pragma unroll
            for (int ni = 0; ni < 4; ++ni) {
                const int colb = wv * 128 + ni * 32 + g * 8;     // residual byte col
                uint2 rx = *(const uint2*)(lds + rb + (colb ^ sw));
                float x0 = __uint_as_float(rx.x << 16);
                float x1 = __uint_as_float(rx.x & 0xFFFF0000u);
                float x2 = __uint_as_float(rx.y << 16);
                float x3 = __uint_as_float(rx.y & 0xFFFF0000u);
                float4 o;
                o.x = gm * (acc[mi][ni][0] + bias4[ni].x) + x0;
                o.y = gm * (acc[mi][ni][1] + bias4[ni].y) + x1;
                o.z = gm * (acc[mi][ni][2] + bias4[ni].z) + x2;
                o.w = gm * (acc[mi][ni][3] + bias4[ni].w) + x3;
                *(float4*)(out + (row0 + row) * 256 + wv * 64 + ni * 16 + g * 4) = o;
            }
        }

        __syncthreads();
        if (!pf) break;
#pragma unroll
        for (int i = 0; i < 16; ++i) {
            int row = i * 4 + wv;
            int addr = row * 512 + ((lane * 8) ^ ((row & 7) << 4));
            uint2 pk;
            pk.x = f2bf(ld[i].x) | (f2bf(ld[i].y) << 16);
            pk.y = f2bf(ld[i].z) | (f2bf(ld[i].w) << 16);
            *(uint2*)(lds + addr) = pk;
        }
        __syncthreads();
        t = t2;
    }
}

extern "C" void kernel_launch(void* const* d_in, const int* in_sizes, int n_in,
                              void* d_out, int out_size, void* d_ws, size_t ws_size,
                              hipStream_t stream) {
    const float* x  = (const float*)d_in[0];
    const float* Wh = (const float*)d_in[5];
    const float* bh = (const float*)d_in[6];
    const float* gm = (const float*)d_in[7];
    float* out = (float*)d_out;
    ushort* whT = (ushort*)d_ws;   // 128 KB scratch

    prep_whT<<<256, 256, 0, stream>>>(Wh, whT);
    ccsa_gemm<<<NBLK, 256, 0, stream>>>(x, whT, bh, gm, out);
}

// Round 6
// 136.243 us; speedup vs baseline: 1.6584x; 1.6584x over previous
//
#include <hip/hip_runtime.h>

typedef __attribute__((ext_vector_type(8))) short bf16x8;
typedef __attribute__((ext_vector_type(4))) float f32x4;

__device__ __forceinline__ unsigned f2bf(float f) {
    union { float f; unsigned u; } v; v.f = f;
    return (v.u + 0x7FFFu + ((v.u >> 16) & 1u)) >> 16;
}

// prep: whT[n][k] = bf16(Wh[k][n]); block=k (coalesced read), thread=n
__global__ void prep_whT(const float* __restrict__ Wh, ushort* __restrict__ whT) {
    int k = blockIdx.x;
    int n = threadIdx.x;
    whT[n * 256 + k] = (ushort)f2bf(Wh[k * 256 + n]);
}

#define NTILE 2048
#define NBLK  512   // 2 blocks/CU exactly, 4 tiles each -> zero tail imbalance

// persistent: each block sweeps tiles {b, b+512, b+1024, b+1536}; next tile's
// x is prefetched into registers at loop top (launch_bounds(256,2) -> 256-reg
// unified budget, NO spill) and written to LDS after the epilogue barrier.
__global__ __launch_bounds__(256, 2) void ccsa_gemm(
    const float* __restrict__ x, const ushort* __restrict__ whT,
    const float* __restrict__ bh, const float* __restrict__ gamma,
    float* __restrict__ out)
{
    __shared__ char lds[32768];              // A tile 64x256 bf16, XOR-swizzled
    const int tid  = threadIdx.x;
    const int lane = tid & 63;
    const int wv   = tid >> 6;
    const int r15  = lane & 15;
    const int g    = lane >> 4;

    const float gm = gamma[0];

    // whT fragment pointers (tile-invariant): A-operand rows n = wv*64+ni*16+r15
    const ushort* bp[4];
#pragma unroll
    for (int ni = 0; ni < 4; ++ni)
        bp[ni] = whT + (wv * 64 + ni * 16 + r15) * 256 + g * 8;

    // bias: 4 consecutive output cols per lane (n = wv*64+ni*16+g*4+rr)
    float4 bias4[4];
#pragma unroll
    for (int ni = 0; ni < 4; ++ni)
        bias4[ni] = *(const float4*)(bh + wv * 64 + ni * 16 + g * 4);

    float4 ld[16];
    long t = blockIdx.x;

    // ---- prologue: stage tile t (only exposed-latency staging) ----
    {
        const float* src = x + t * 16384 + tid * 4;
#pragma unroll
        for (int i = 0; i < 16; ++i) ld[i] = *(const float4*)(src + i * 1024);
    }
#pragma unroll
    for (int i = 0; i < 16; ++i) {
        int row = i * 4 + wv;
        int addr = row * 512 + ((lane * 8) ^ ((row & 7) << 4));
        uint2 pk;
        pk.x = f2bf(ld[i].x) | (f2bf(ld[i].y) << 16);
        pk.y = f2bf(ld[i].z) | (f2bf(ld[i].w) << 16);
        *(uint2*)(lds + addr) = pk;
    }
    __syncthreads();

    while (true) {
        const long t2 = t + NBLK;
        const bool pf = (t2 < NTILE);

        // prefetch next tile into registers NOW; consumed after epilogue+barrier
        if (pf) {
            const float* src = x + t2 * 16384 + tid * 4;
#pragma unroll
            for (int i = 0; i < 16; ++i) ld[i] = *(const float4*)(src + i * 1024);
        }

        f32x4 acc[4][4] = {};   // [mi][ni]; D rows = n (whT), D cols = m (x)

#pragma unroll
        for (int ksl = 0; ksl < 8; ++ksl) {
            bf16x8 bc[4], af[4];
#pragma unroll
            for (int ni = 0; ni < 4; ++ni)
                bc[ni] = *(const bf16x8*)(bp[ni] + ksl * 32);
            const int ko = (ksl * 64 + g * 16) ^ ((r15 & 7) << 4);
#pragma unroll
            for (int mi = 0; mi < 4; ++mi)
                af[mi] = *(const bf16x8*)(lds + (mi * 16 + r15) * 512 + ko);
#pragma unroll
            for (int mi = 0; mi < 4; ++mi)
#pragma unroll
                for (int ni = 0; ni < 4; ++ni)
                    acc[mi][ni] = __builtin_amdgcn_mfma_f32_16x16x32_bf16(
                        bc[ni], af[mi], acc[mi][ni], 0, 0, 0);
        }

        // ---- epilogue: out = gm*(acc + bias) + x, float4 stores ----
        const long row0 = t * 64;
#pragma unroll
        for (int mi = 0; mi < 4; ++mi) {
            const int row = mi * 16 + r15;
            const int rb  = row * 512;
            const int sw  = (row & 7) << 4;
#pragma unroll
            for (int ni = 0; ni < 4; ++ni) {
                const int colb = wv * 128 + ni * 32 + g * 8;     // residual byte col
                uint2 rx = *(const uint2*)(lds + rb + (colb ^ sw));
                float x0 = __uint_as_float(rx.x << 16);
                float x1 = __uint_as_float(rx.x & 0xFFFF0000u);
                float x2 = __uint_as_float(rx.y << 16);
                float x3 = __uint_as_float(rx.y & 0xFFFF0000u);
                float4 o;
                o.x = gm * (acc[mi][ni][0] + bias4[ni].x) + x0;
                o.y = gm * (acc[mi][ni][1] + bias4[ni].y) + x1;
                o.z = gm * (acc[mi][ni][2] + bias4[ni].z) + x2;
                o.w = gm * (acc[mi][ni][3] + bias4[ni].w) + x3;
                *(float4*)(out + (row0 + row) * 256 + wv * 64 + ni * 16 + g * 4) = o;
            }
        }

        __syncthreads();
        if (!pf) break;
#pragma unroll
        for (int i = 0; i < 16; ++i) {
            int row = i * 4 + wv;
            int addr = row * 512 + ((lane * 8) ^ ((row & 7) << 4));
            uint2 pk;
            pk.x = f2bf(ld[i].x) | (f2bf(ld[i].y) << 16);
            pk.y = f2bf(ld[i].z) | (f2bf(ld[i].w) << 16);
            *(uint2*)(lds + addr) = pk;
        }
        __syncthreads();
        t = t2;
    }
}

extern "C" void kernel_launch(void* const* d_in, const int* in_sizes, int n_in,
                              void* d_out, int out_size, void* d_ws, size_t ws_size,
                              hipStream_t stream) {
    const float* x  = (const float*)d_in[0];
    const float* Wh = (const float*)d_in[5];
    const float* bh = (const float*)d_in[6];
    const float* gm = (const float*)d_in[7];
    float* out = (float*)d_out;
    ushort* whT = (ushort*)d_ws;   // 128 KB scratch

    prep_whT<<<256, 256, 0, stream>>>(Wh, whT);
    ccsa_gemm<<<NBLK, 256, 0, stream>>>(x, whT, bh, gm, out);
}

// Round 7
// 126.674 us; speedup vs baseline: 1.7837x; 1.0755x over previous
//
#include <hip/hip_runtime.h>

typedef __attribute__((ext_vector_type(8))) short bf16x8;
typedef __attribute__((ext_vector_type(4))) float f32x4;

__device__ __forceinline__ unsigned f2bf(float f) {
    union { float f; unsigned u; } v; v.f = f;
    return (v.u + 0x7FFFu + ((v.u >> 16) & 1u)) >> 16;
}

// prep: whT[n][k] = bf16(Wh[k][n]); block=k (coalesced read), thread=n
__global__ void prep_whT(const float* __restrict__ Wh, ushort* __restrict__ whT) {
    int k = blockIdx.x;
    int n = threadIdx.x;
    whT[n * 256 + k] = (ushort)f2bf(Wh[k * 256 + n]);
}

// out = gamma*(x@Wh + bh) + x
// No LDS, no barriers: A fragments (8 contiguous fp32 of x) and the fp32
// residual are loaded straight from global (L1/L3-cached); B fragments from
// L2-resident whT. Swapped MFMA operands -> float4 epilogue stores.
__global__ __launch_bounds__(256, 3) void ccsa_gemm(
    const float* __restrict__ x, const ushort* __restrict__ whT,
    const float* __restrict__ bh, const float* __restrict__ gamma,
    float* __restrict__ out)
{
    const int tid  = threadIdx.x;
    const int lane = tid & 63;
    const int wv   = tid >> 6;
    const int r15  = lane & 15;
    const int g    = lane >> 4;

    const float gm = gamma[0];

    // whT fragment pointers: A-operand rows n = wv*64 + ni*16 + r15, k off g*8
    const ushort* bp[4];
#pragma unroll
    for (int ni = 0; ni < 4; ++ni)
        bp[ni] = whT + (wv * 64 + ni * 16 + r15) * 256 + g * 8;

    // bias: 4 consecutive output cols per lane
    float4 bias4[4];
#pragma unroll
    for (int ni = 0; ni < 4; ++ni)
        bias4[ni] = *(const float4*)(bh + wv * 64 + ni * 16 + g * 4);

    const long row0 = (long)blockIdx.x * 64;
    // per-lane A base: row = row0 + mi*16 + r15, k = ksl*32 + g*8
    const float* xa = x + (row0 + r15) * 256 + g * 8;

    f32x4 acc[4][4] = {};   // [mi][ni]; D row dim = n (whT), D col dim = m (x row)

#pragma unroll
    for (int ksl = 0; ksl < 8; ++ksl) {
        bf16x8 bc[4];
#pragma unroll
        for (int ni = 0; ni < 4; ++ni)
            bc[ni] = *(const bf16x8*)(bp[ni] + ksl * 32);

        bf16x8 af[4];
#pragma unroll
        for (int mi = 0; mi < 4; ++mi) {
            const float* ap = xa + mi * 4096 + ksl * 32;     // mi*16 rows * 256
            float4 a0 = *(const float4*)(ap);
            float4 a1 = *(const float4*)(ap + 4);
            union { uint4 u; bf16x8 h; } cv;
            cv.u.x = f2bf(a0.x) | (f2bf(a0.y) << 16);
            cv.u.y = f2bf(a0.z) | (f2bf(a0.w) << 16);
            cv.u.z = f2bf(a1.x) | (f2bf(a1.y) << 16);
            cv.u.w = f2bf(a1.z) | (f2bf(a1.w) << 16);
            af[mi] = cv.h;
        }

#pragma unroll
        for (int mi = 0; mi < 4; ++mi)
#pragma unroll
            for (int ni = 0; ni < 4; ++ni)
                acc[mi][ni] = __builtin_amdgcn_mfma_f32_16x16x32_bf16(
                    bc[ni], af[mi], acc[mi][ni], 0, 0, 0);
    }

    // epilogue: out = gm*(acc + bias) + x (fp32 residual direct from global)
#pragma unroll
    for (int mi = 0; mi < 4; ++mi) {
        const long rbase = (row0 + mi * 16 + r15) * 256;
#pragma unroll
        for (int ni = 0; ni < 4; ++ni) {
            const int col = wv * 64 + ni * 16 + g * 4;
            float4 rx = *(const float4*)(x + rbase + col);
            float4 o;
            o.x = gm * (acc[mi][ni][0] + bias4[ni].x) + rx.x;
            o.y = gm * (acc[mi][ni][1] + bias4[ni].y) + rx.y;
            o.z = gm * (acc[mi][ni][2] + bias4[ni].z) + rx.z;
            o.w = gm * (acc[mi][ni][3] + bias4[ni].w) + rx.w;
            *(float4*)(out + rbase + col) = o;
        }
    }
}

extern "C" void kernel_launch(void* const* d_in, const int* in_sizes, int n_in,
                              void* d_out, int out_size, void* d_ws, size_t ws_size,
                              hipStream_t stream) {
    const float* x  = (const float*)d_in[0];
    const float* Wh = (const float*)d_in[5];
    const float* bh = (const float*)d_in[6];
    const float* gm = (const float*)d_in[7];
    float* out = (float*)d_out;
    ushort* whT = (ushort*)d_ws;   // 128 KB scratch

    prep_whT<<<256, 256, 0, stream>>>(Wh, whT);
    ccsa_gemm<<<2048, 256, 0, stream>>>(x, whT, bh, gm, out);
}